// Round 8
// baseline (81.460 us; speedup 1.0000x reference)
//
#include <hip/hip_runtime.h>

typedef unsigned int uint;

#define HW (512 * 512)
#define NIMG 64
#define NUQ 6
#define NBAND 8            // 64-row bands per image -> 512 blocks

// offsets (all reformulated so every pair references rows <= current; (1,-1)
// recorded as (-1,1), transpose-equivalent under final P+P^T symmetrization):
// u0 (0,1)  w1 tag0 lo | u1 (1,1) w2 tag1 lo | u2 (1,0) w1 tag2 lo
// u3 (-1,1) w2 tag0 hi | u4 (0,2) w1 tag1 hi | u5 (2,0) w1 tag2 hi
__device__ __constant__ float UOFF_W[NUQ] = {1.f, 2.f, 1.f, 2.f, 1.f, 1.f};
__device__ __constant__ float NPAIRS[NUQ] = {
    512.f * 511.f, 511.f * 511.f, 511.f * 512.f,
    511.f * 511.f, 512.f * 510.f, 510.f * 512.f};

__device__ __forceinline__ uint q1f(float a, float b, float c) {
    // ((a+b+c)/3 + 1) * 0.5 * 31 == (a+b+c)*(31/6) + 15.5
    float t = fmaf(a + b + c, 5.1666665f, 15.5f);
    t = fminf(fmaxf(t, 0.0f), 31.0f);
    return (uint)t;                       // trunc, matches astype(int32)
}

// ---- fused: quantize + histogram, register-resident row walk, no barriers ----
__global__ __launch_bounds__(256) void glcm_fused(
    const float* __restrict__ in, uint* __restrict__ wire) {
    __shared__ __align__(16) uint hist[8192];   // 32 KB: i(5b) x tag(2b) x 256B
    const int tid = threadIdx.x;
    const int b = blockIdx.x >> 3;
    const int band = blockIdx.x & 7;
    const int cg = tid & 31;              // col group (16 px)
    const int ts = tid >> 5;              // row strip within band (8 rows)
    const int r0 = band * 64 + ts * 8;
    const int c0 = cg << 4;
    const float* ib = in + (size_t)b * (3 * HW);
    unsigned char* hb8 = (unsigned char*)hist;

    {
        uint4 z = make_uint4(0, 0, 0, 0);
        #pragma unroll
        for (int q = 0; q < 8; ++q)
            *(uint4*)(hb8 + tid * 16 + q * 4096) = z;
    }
    __syncthreads();

    // quantize one row into 5 packed words (20 cols, bytes pre-shifted <<2)
    auto qrow = [&](int r, uint w[5]) {
        const float* base = ib + ((size_t)r << 9);
        #pragma unroll
        for (int k = 0; k < 5; ++k) {
            int cc = (k < 4) ? (c0 + 4 * k) : min(c0 + 16, 508);
            float4 f0 = *(const float4*)(base + cc);
            float4 f1 = *(const float4*)(base + HW + cc);
            float4 f2 = *(const float4*)(base + 2 * HW + cc);
            w[k] = (q1f(f0.x, f1.x, f2.x) << 2)
                 | (q1f(f0.y, f1.y, f2.y) << 10)
                 | (q1f(f0.z, f1.z, f2.z) << 18)
                 | (q1f(f0.w, f1.w, f2.w) << 26);
        }
        if (cg == 31) w[4] = 0x80808080u;   // cols 512+ -> junk-bin sentinel
    };

    // one pair-word: addr = (qi<<10)|(tag<<8)|(qj<<2); sentinel 0x80 -> bit7 junk
    auto pp = [&](uint IW, uint JW, int tagoff, uint inc) {
        uint a0 = __builtin_amdgcn_perm(IW, JW, 0x0C0C0400u) & 0xFCFCu;
        uint a1 = __builtin_amdgcn_perm(IW, JW, 0x0C0C0501u) & 0xFCFCu;
        uint a2 = __builtin_amdgcn_perm(IW, JW, 0x0C0C0602u) & 0xFCFCu;
        uint a3 = __builtin_amdgcn_perm(IW, JW, 0x0C0C0703u) & 0xFCFCu;
        atomicAdd((uint*)(hb8 + tagoff + a0), inc);
        atomicAdd((uint*)(hb8 + tagoff + a1), inc);
        atomicAdd((uint*)(hb8 + tagoff + a2), inc);
        atomicAdd((uint*)(hb8 + tagoff + a3), inc);
    };

    uint p2[5] = {0, 0, 0, 0, 0}, p1[5] = {0, 0, 0, 0, 0}, cur[5];
    if (r0 >= 2) qrow(r0 - 2, p2);        // prime history (overlap rows)
    if (r0 >= 1) qrow(r0 - 1, p1);

    for (int it = 0; it < 8; ++it) {
        const int r = r0 + it;
        qrow(r, cur);

        #pragma unroll
        for (int k = 0; k < 4; ++k) {     // i-words: owned 16 cols (always valid)
            uint C1 = __builtin_amdgcn_alignbyte(cur[k + 1], cur[k], 1);
            uint C2 = __builtin_amdgcn_alignbyte(cur[k + 1], cur[k], 2);
            pp(cur[k], C1, 0,   1u);      // u0 (0,1)
            pp(cur[k], C2, 256, 65536u);  // u4 (0,2)
        }
        if (r >= 1) {
            #pragma unroll
            for (int k = 0; k < 4; ++k) {
                uint C1 = __builtin_amdgcn_alignbyte(cur[k + 1], cur[k], 1);
                uint P1 = __builtin_amdgcn_alignbyte(p1[k + 1], p1[k], 1);
                pp(p1[k], cur[k], 512, 1u);      // u2 (1,0)
                pp(p1[k], C1,     256, 1u);      // u1 (1,1)
                pp(cur[k], P1,    0,   65536u);  // u3 (-1,1)
            }
            if (r >= 2) {
                #pragma unroll
                for (int k = 0; k < 4; ++k)
                    pp(p2[k], cur[k], 512, 65536u);  // u5 (2,0)
            }
        }
        #pragma unroll
        for (int k = 0; k < 5; ++k) { p2[k] = p1[k]; p1[k] = cur[k]; }
    }
    __syncthreads();

    // flush valid bins (j<32 dwords only) -> 3072-dword wire, plain stores
    uint* hw = wire + (size_t)blockIdx.x * 3072;
    #pragma unroll
    for (int qq = 0; qq < 12; ++qq) {
        int o = tid + qq * 256;           // o = tag*1024 + i*32 + j
        int tg = o >> 10, ij = o & 1023;
        int i = ij >> 5, j = ij & 31;
        hw[o] = hist[(i << 8) | (tg << 6) | j];
    }
}

// ---- features + weighted offset average, one block per image ----
__global__ __launch_bounds__(256) void feature_out_kernel(
    const uint* __restrict__ wire, float* __restrict__ out) {
    const int b = blockIdx.x;
    __shared__ uint cnt[NUQ][1024];       // 24 KB
    __shared__ float fred[NUQ][4];
    const int tid = threadIdx.x, wid = tid >> 6, lane = tid & 63;

    for (int u = wid; u < NUQ; u += 4) {
        const int tg = (u < 3) ? u : u - 3;
        const int sh = (u < 3) ? 0 : 16;
        const uint* p = wire + (size_t)b * (NBAND * 3072) + tg * 1024;
        for (int ij = lane; ij < 1024; ij += 64) {
            uint acc = 0;
            #pragma unroll
            for (int st = 0; st < NBAND; ++st)
                acc += (p[(size_t)st * 3072 + ij] >> sh) & 0xFFFFu;
            cnt[u][ij] = acc;
        }
    }
    __syncthreads();

    for (int u = wid; u < NUQ; u += 4) {
        const float inv_total = 1.0f / (2.0f * NPAIRS[u]);
        float c_sum = 0, h_sum = 0, e_sum = 0, m1 = 0, m2 = 0, m12 = 0;
        for (int k = lane; k < 1024; k += 64) {
            int i = k >> 5, j = k & 31;
            float sym = (float)(cnt[u][k] + cnt[u][(j << 5) | i]);
            float P = sym * inv_total;
            float d = (float)(i - j);
            float d2 = d * d;
            float fi = (float)i, fj = (float)j;
            c_sum += P * d2;
            h_sum += P / (1.0f + d2);
            e_sum += P * P;
            m1 += P * fi; m2 += P * fi * fi; m12 += P * fi * fj;
        }
        #pragma unroll
        for (int sft = 32; sft > 0; sft >>= 1) {
            c_sum += __shfl_down(c_sum, sft);
            h_sum += __shfl_down(h_sum, sft);
            e_sum += __shfl_down(e_sum, sft);
            m1 += __shfl_down(m1, sft);
            m2 += __shfl_down(m2, sft);
            m12 += __shfl_down(m12, sft);
        }
        if (lane == 0) {
            float mu = m1, var = m2 - mu * mu, cov = m12 - mu * mu;
            float corr = (var > 1e-15f) ? cov / var : 1.0f;  // std_i*std_j = var
            fred[u][0] = c_sum; fred[u][1] = h_sum;
            fred[u][2] = sqrtf(e_sum); fred[u][3] = corr;
        }
    }
    __syncthreads();
    if (tid < 4) {
        float acc = 0.f;
        #pragma unroll
        for (int u = 0; u < NUQ; ++u) acc += UOFF_W[u] * fred[u][tid];
        out[tid * NIMG + b] = acc * 0.125f;
    }
}

extern "C" void kernel_launch(void* const* d_in, const int* in_sizes, int n_in,
                              void* d_out, int out_size, void* d_ws, size_t ws_size,
                              hipStream_t stream) {
    const float* images = (const float*)d_in[0];
    float* out = (float*)d_out;
    uint* wire = (uint*)d_ws;             // 512 blocks x 3072 u32 = 6.3 MB

    glcm_fused<<<NIMG * NBAND, 256, 0, stream>>>(images, wire);
    feature_out_kernel<<<NIMG, 256, 0, stream>>>(wire, out);
}

// Round 9
// 80.230 us; speedup vs baseline: 1.0153x; 1.0153x over previous
//
#include <hip/hip_runtime.h>

typedef unsigned int uint;

#define HW (512 * 512)
#define NIMG 64
#define NUQ 6
#define NBAND 8            // 64-row bands per image -> 512 blocks

// offsets (all reformulated so every pair references rows <= current; (1,-1)
// recorded as (-1,1), transpose-equivalent under final P+P^T symmetrization):
// u0 (0,1)  w1 tag0 lo | u1 (1,1) w2 tag1 lo | u2 (1,0) w1 tag2 lo
// u3 (-1,1) w2 tag0 hi | u4 (0,2) w1 tag1 hi | u5 (2,0) w1 tag2 hi
__device__ __constant__ float UOFF_W[NUQ] = {1.f, 2.f, 1.f, 2.f, 1.f, 1.f};
__device__ __constant__ float NPAIRS[NUQ] = {
    512.f * 511.f, 511.f * 511.f, 511.f * 512.f,
    511.f * 511.f, 512.f * 510.f, 510.f * 512.f};

__device__ __forceinline__ uint q1f(float a, float b, float c) {
    // ((a+b+c)/3 + 1) * 0.5 * 31 == (a+b+c)*(31/6) + 15.5
    float t = fmaf(a + b + c, 5.1666665f, 15.5f);
    t = fminf(fmaxf(t, 0.0f), 31.0f);
    return (uint)t;                       // trunc, matches astype(int32)
}

// ---- fused: quantize + histogram, register-resident row walk, no barriers ----
__global__ __launch_bounds__(256) void glcm_fused(
    const float* __restrict__ in, uint* __restrict__ wire) {
    __shared__ __align__(16) uint hist[8192];   // 32 KB: i(5b) x tag(2b) x 256B
    const int tid = threadIdx.x;
    const int b = blockIdx.x >> 3;
    const int band = blockIdx.x & 7;
    const int cg = tid & 31;              // col group (16 px)
    const int ts = tid >> 5;              // row strip within band (8 rows)
    const int r0 = band * 64 + ts * 8;
    const int c0 = cg << 4;
    const float* ib = in + (size_t)b * (3 * HW);
    unsigned char* hb8 = (unsigned char*)hist;

    {
        uint4 z = make_uint4(0, 0, 0, 0);
        #pragma unroll
        for (int q = 0; q < 8; ++q)
            *(uint4*)(hb8 + tid * 16 + q * 4096) = z;
    }
    __syncthreads();

    // quantize one row into 5 packed words (20 cols, bytes pre-shifted <<2)
    auto qrow = [&](int r, uint w[5]) {
        const float* base = ib + ((size_t)r << 9);
        #pragma unroll
        for (int k = 0; k < 5; ++k) {
            int cc = (k < 4) ? (c0 + 4 * k) : min(c0 + 16, 508);
            float4 f0 = *(const float4*)(base + cc);
            float4 f1 = *(const float4*)(base + HW + cc);
            float4 f2 = *(const float4*)(base + 2 * HW + cc);
            w[k] = (q1f(f0.x, f1.x, f2.x) << 2)
                 | (q1f(f0.y, f1.y, f2.y) << 10)
                 | (q1f(f0.z, f1.z, f2.z) << 18)
                 | (q1f(f0.w, f1.w, f2.w) << 26);
        }
        if (cg == 31) w[4] = 0x80808080u;   // cols 512+ -> junk-bin sentinel
    };

    // one pair-word group (4 pairs). SWAR bank-mix: stored j-field =
    // (j + 2i) & 31  -> LDS bank = near-uniform mix of i,j (Gaussian-peaked
    // j alone was a ~3x bank conflict). Bijective per i; un-mixed at flush.
    // Sentinel bit7 preserved -> junk region (dwords 32-63 per i,tag row).
    auto pp = [&](uint IW, uint JW, int tagoff, uint inc) {
        uint jm = (JW >> 2) & 0x1F1F1F1Fu;   // j per byte (sentinel -> 0)
        uint im = (IW >> 1) & 0x3E3E3E3Eu;   // 2*i per byte
        uint s  = (jm + im) & 0x1F1F1F1Fu;   // (j + 2i) & 31, no cross-byte carry
        uint JW2 = (s << 2) | (JW & 0x80808080u);
        uint a0 = __builtin_amdgcn_perm(IW, JW2, 0x0C0C0400u) & 0xFCFCu;
        uint a1 = __builtin_amdgcn_perm(IW, JW2, 0x0C0C0501u) & 0xFCFCu;
        uint a2 = __builtin_amdgcn_perm(IW, JW2, 0x0C0C0602u) & 0xFCFCu;
        uint a3 = __builtin_amdgcn_perm(IW, JW2, 0x0C0C0703u) & 0xFCFCu;
        atomicAdd((uint*)(hb8 + tagoff + a0), inc);
        atomicAdd((uint*)(hb8 + tagoff + a1), inc);
        atomicAdd((uint*)(hb8 + tagoff + a2), inc);
        atomicAdd((uint*)(hb8 + tagoff + a3), inc);
    };

    uint p2[5] = {0, 0, 0, 0, 0}, p1[5] = {0, 0, 0, 0, 0}, cur[5];
    if (r0 >= 2) qrow(r0 - 2, p2);        // prime history (overlap rows)
    if (r0 >= 1) qrow(r0 - 1, p1);

    for (int it = 0; it < 8; ++it) {
        const int r = r0 + it;
        qrow(r, cur);

        #pragma unroll
        for (int k = 0; k < 4; ++k) {     // i-words: owned 16 cols (always valid)
            uint C1 = __builtin_amdgcn_alignbyte(cur[k + 1], cur[k], 1);
            uint C2 = __builtin_amdgcn_alignbyte(cur[k + 1], cur[k], 2);
            pp(cur[k], C1, 0,   1u);      // u0 (0,1)
            pp(cur[k], C2, 256, 65536u);  // u4 (0,2)
        }
        if (r >= 1) {
            #pragma unroll
            for (int k = 0; k < 4; ++k) {
                uint C1 = __builtin_amdgcn_alignbyte(cur[k + 1], cur[k], 1);
                uint P1 = __builtin_amdgcn_alignbyte(p1[k + 1], p1[k], 1);
                pp(p1[k], cur[k], 512, 1u);      // u2 (1,0)
                pp(p1[k], C1,     256, 1u);      // u1 (1,1)
                pp(cur[k], P1,    0,   65536u);  // u3 (-1,1)
            }
            if (r >= 2) {
                #pragma unroll
                for (int k = 0; k < 4; ++k)
                    pp(p2[k], cur[k], 512, 65536u);  // u5 (2,0)
            }
        }
        #pragma unroll
        for (int k = 0; k < 5; ++k) { p2[k] = p1[k]; p1[k] = cur[k]; }
    }
    __syncthreads();

    // flush valid bins -> 3072-dword wire, un-mixing the j-field permutation
    uint* hw = wire + (size_t)blockIdx.x * 3072;
    #pragma unroll
    for (int qq = 0; qq < 12; ++qq) {
        int o = tid + qq * 256;           // o = tag*1024 + i*32 + j
        int tg = o >> 10, ij = o & 1023;
        int i = ij >> 5, j = ij & 31;
        hw[o] = hist[(i << 8) | (tg << 6) | ((j + 2 * i) & 31)];
    }
}

// ---- features + weighted offset average, one block per image ----
__global__ __launch_bounds__(256) void feature_out_kernel(
    const uint* __restrict__ wire, float* __restrict__ out) {
    const int b = blockIdx.x;
    __shared__ uint cnt[NUQ][1024];       // 24 KB
    __shared__ float fred[NUQ][4];
    const int tid = threadIdx.x, wid = tid >> 6, lane = tid & 63;

    for (int u = wid; u < NUQ; u += 4) {
        const int tg = (u < 3) ? u : u - 3;
        const int sh = (u < 3) ? 0 : 16;
        const uint* p = wire + (size_t)b * (NBAND * 3072) + tg * 1024;
        for (int ij = lane; ij < 1024; ij += 64) {
            uint acc = 0;
            #pragma unroll
            for (int st = 0; st < NBAND; ++st)
                acc += (p[(size_t)st * 3072 + ij] >> sh) & 0xFFFFu;
            cnt[u][ij] = acc;
        }
    }
    __syncthreads();

    for (int u = wid; u < NUQ; u += 4) {
        const float inv_total = 1.0f / (2.0f * NPAIRS[u]);
        float c_sum = 0, h_sum = 0, e_sum = 0, m1 = 0, m2 = 0, m12 = 0;
        for (int k = lane; k < 1024; k += 64) {
            int i = k >> 5, j = k & 31;
            float sym = (float)(cnt[u][k] + cnt[u][(j << 5) | i]);
            float P = sym * inv_total;
            float d = (float)(i - j);
            float d2 = d * d;
            float fi = (float)i, fj = (float)j;
            c_sum += P * d2;
            h_sum += P / (1.0f + d2);
            e_sum += P * P;
            m1 += P * fi; m2 += P * fi * fi; m12 += P * fi * fj;
        }
        #pragma unroll
        for (int sft = 32; sft > 0; sft >>= 1) {
            c_sum += __shfl_down(c_sum, sft);
            h_sum += __shfl_down(h_sum, sft);
            e_sum += __shfl_down(e_sum, sft);
            m1 += __shfl_down(m1, sft);
            m2 += __shfl_down(m2, sft);
            m12 += __shfl_down(m12, sft);
        }
        if (lane == 0) {
            float mu = m1, var = m2 - mu * mu, cov = m12 - mu * mu;
            float corr = (var > 1e-15f) ? cov / var : 1.0f;  // std_i*std_j = var
            fred[u][0] = c_sum; fred[u][1] = h_sum;
            fred[u][2] = sqrtf(e_sum); fred[u][3] = corr;
        }
    }
    __syncthreads();
    if (tid < 4) {
        float acc = 0.f;
        #pragma unroll
        for (int u = 0; u < NUQ; ++u) acc += UOFF_W[u] * fred[u][tid];
        out[tid * NIMG + b] = acc * 0.125f;
    }
}

extern "C" void kernel_launch(void* const* d_in, const int* in_sizes, int n_in,
                              void* d_out, int out_size, void* d_ws, size_t ws_size,
                              hipStream_t stream) {
    const float* images = (const float*)d_in[0];
    float* out = (float*)d_out;
    uint* wire = (uint*)d_ws;             // 512 blocks x 3072 u32 = 6.3 MB

    glcm_fused<<<NIMG * NBAND, 256, 0, stream>>>(images, wire);
    feature_out_kernel<<<NIMG, 256, 0, stream>>>(wire, out);
}

// Round 10
// 74.045 us; speedup vs baseline: 1.1001x; 1.0835x over previous
//
#include <hip/hip_runtime.h>

typedef unsigned int uint;

#define HW (512 * 512)
#define NIMG 64
#define NUQ 6
#define RSTRIDE 528                       // ring row: 512 px + 16 sentinel bytes
#define RINGROWS 16
#define RINGBYTES (RINGROWS * RSTRIDE)    // 8448
#define RINGA 32768
#define RINGB (32768 + RINGBYTES)
#define SMEMB (32768 + 2 * RINGBYTES)     // 49664

// 8 reference offsets -> 6 unique, weighted; (1,-1) stored as (-1,1)
// (transpose-equivalent under final P+P^T symmetrization).
// u0 (0,1) tag0 lo | u1 (1,1) tag1 lo | u2 (1,0) tag2 lo
// u3 (-1,1) tag0 hi | u4 (0,2) tag1 hi | u5 (2,0) tag2 hi
__device__ __constant__ float UOFF_W[NUQ] = {1.f, 2.f, 1.f, 2.f, 1.f, 1.f};
__device__ __constant__ float NPAIRS[NUQ] = {
    512.f * 511.f, 511.f * 511.f, 511.f * 512.f,
    511.f * 511.f, 512.f * 510.f, 510.f * 512.f};

__device__ __forceinline__ uint q1f(float a, float b, float c) {
    float t = fmaf(a + b + c, 5.1666665f, 15.5f);   // ((a+b+c)/3+1)*0.5*31
    t = fminf(fmaxf(t, 0.0f), 31.0f);
    return (uint)t;                                  // trunc = astype(int32)
}

// ---- fused: dual-strip interleave; every interval = HBM stream + DS stream ----
__global__ __launch_bounds__(256) void glcm_fused(
    const float* __restrict__ in, uint* __restrict__ wire) {
    __shared__ __align__(16) unsigned char smem[SMEMB];
    const int tid = threadIdx.x;
    const int b = blockIdx.x >> 3;
    const int sp = blockIdx.x & 7;
    const int rsA = sp * 32;
    const int rsB = sp * 32 + 256;
    const float* ib = in + (size_t)b * (3 * HW);
    const int lrow = tid >> 6;            // wave id = row within 4-row chunk
    const int lcol = (tid & 63) << 3;     // 8 px per thread

    {   // zero 32 KB hist (junk bins included)
        uint4 z = make_uint4(0, 0, 0, 0);
        #pragma unroll
        for (int q = 0; q < 8; ++q)
            *(uint4*)(smem + tid * 16 + q * 4096) = z;
    }
    __syncthreads();

    // issue 6 float4 loads for chunk c of strip rs (rows rs-2+4c .. +3)
    auto issueL = [&](int rs, int c, float4& A0, float4& B0, float4& A1,
                      float4& B1, float4& A2, float4& B2) {
        int R = rs - 2 + 4 * c + lrow;
        int Rc = min(max(R, 0), 511);     // clamped rows loaded, never written
        const float* p = ib + ((size_t)Rc << 9) + lcol;
        A0 = *(const float4*)(p);
        B0 = *(const float4*)(p + 4);
        A1 = *(const float4*)(p + HW);
        B1 = *(const float4*)(p + HW + 4);
        A2 = *(const float4*)(p + 2 * HW);
        B2 = *(const float4*)(p + 2 * HW + 4);
    };

    // quantize chunk c into ring (bytes pre-shifted <<2) + sentinel pads
    auto quantW = [&](int rs, int ringo, int c, const float4& A0, const float4& B0,
                      const float4& A1, const float4& B1, const float4& A2,
                      const float4& B2) {
        int R = rs - 2 + 4 * c + lrow;
        if (R >= 0 && R <= 511) {
            uint q0 = (q1f(A0.x, A1.x, A2.x) << 2)
                    | (q1f(A0.y, A1.y, A2.y) << 10)
                    | (q1f(A0.z, A1.z, A2.z) << 18)
                    | (q1f(A0.w, A1.w, A2.w) << 26);
            uint q1_ = (q1f(B0.x, B1.x, B2.x) << 2)
                     | (q1f(B0.y, B1.y, B2.y) << 10)
                     | (q1f(B0.z, B1.z, B2.z) << 18)
                     | (q1f(B0.w, B1.w, B2.w) << 26);
            unsigned char* rw = smem + ringo + ((R + 2) & 15) * RSTRIDE;
            *(uint2*)(rw + lcol) = make_uint2(q0, q1_);
            if ((tid & 63) == 63)         // sentinel cols 512..527
                *(uint4*)(rw + 512) = make_uint4(0x80808080u, 0x80808080u,
                                                 0x80808080u, 0x80808080u);
        }
    };

    // histogram anchors rows [rs+4h, rs+4h+4): 2 rounds x (2 rows x 128 dwords)
    auto histC = [&](int rs, int ringo, int h) {
        const unsigned char* ring = smem + ringo;
        #pragma unroll
        for (int rr = 0; rr < 2; ++rr) {
            const int R = rs + 4 * h + 2 * rr + (tid >> 7);   // wave-uniform
            const int dq = tid & 127;
            const uint* rowL   = (const uint*)(ring + ((R + 2) & 15) * RSTRIDE);
            const uint* rowLm  = (const uint*)(ring + ((R + 1) & 15) * RSTRIDE);
            const uint* rowLp  = (const uint*)(ring + ((R + 3) & 15) * RSTRIDE);
            const uint* rowLpp = (const uint*)(ring + ((R + 4) & 15) * RSTRIDE);
            uint A  = rowL[dq],  A1 = rowL[dq + 1];   // dq=127 -> [128] = pad
            uint Bm = rowLp[dq], B1 = rowLp[dq + 1];
            uint Cm = rowLm[dq], C1 = rowLm[dq + 1];
            uint D  = rowLpp[dq];

            // stored j-field = (j + 3i) & 31 (bank mix, bijective per i);
            // addr16 = i<<10 | junk<<7 | j'<<2; tag adds bits 8-9; sentinel
            // byte 0x80 keeps bit7 -> junk half of each 256B (i,tag) block.
            auto pp4 = [&](uint IW, uint JW, int tagoff, uint inc) {
                uint jm = (JW >> 2) & 0x1F1F1F1Fu;
                uint im = (IW >> 2) & 0x1F1F1F1Fu;
                uint s  = (jm + im + (im << 1)) & 0x1F1F1F1Fu;  // j+3i, no carry
                uint J2 = (s << 2) | (JW & 0x80808080u);
                uint a0 = __builtin_amdgcn_perm(IW, J2, 0x0C0C0400u);
                uint a1 = __builtin_amdgcn_perm(IW, J2, 0x0C0C0501u);
                uint a2 = __builtin_amdgcn_perm(IW, J2, 0x0C0C0602u);
                uint a3 = __builtin_amdgcn_perm(IW, J2, 0x0C0C0703u);
                atomicAdd((uint*)(smem + tagoff + a0), inc);
                atomicAdd((uint*)(smem + tagoff + a1), inc);
                atomicAdd((uint*)(smem + tagoff + a2), inc);
                atomicAdd((uint*)(smem + tagoff + a3), inc);
            };
            if (R < 512) pp4(A, __builtin_amdgcn_alignbyte(A1, A, 1), 0, 1u);        // u0 (0,1)
            if (R < 511) pp4(A, __builtin_amdgcn_alignbyte(B1, Bm, 1), 256, 1u);     // u1 (1,1)
            if (R < 511) pp4(A, Bm, 512, 1u);                                        // u2 (1,0)
            if (R >= 1 && R < 512)
                pp4(A, __builtin_amdgcn_alignbyte(C1, Cm, 1), 0, 65536u);            // u3 (-1,1)
            if (R < 512) pp4(A, __builtin_amdgcn_alignbyte(A1, A, 2), 256, 65536u);  // u4 (0,2)
            if (R < 510) pp4(A, D, 512, 65536u);                                     // u5 (2,0)
        }
    };

    float4 a0, b0, a1, b1, a2, b2;
    for (int i = 0; i < 10; ++i) {
        // sub A: stream strip A from HBM || grind strip B's hist on the DS pipe
        if (i <= 8) issueL(rsA, i, a0, b0, a1, b1, a2, b2);
        if (i >= 2) histC(rsB, RINGB, i - 2);
        if (i <= 8) quantW(rsA, RINGA, i, a0, b0, a1, b1, a2, b2);
        __syncthreads();
        // sub B: stream strip B || grind strip A's hist
        if (i <= 8) issueL(rsB, i, a0, b0, a1, b1, a2, b2);
        if (i >= 2) histC(rsA, RINGA, i - 2);
        if (i <= 8) quantW(rsB, RINGB, i, a0, b0, a1, b1, a2, b2);
        __syncthreads();
    }

    // flush valid bins -> 3072-dword wire, un-mixing the stored j-field
    uint* hw = wire + (size_t)blockIdx.x * 3072;
    const uint* hist = (const uint*)smem;
    #pragma unroll
    for (int qq = 0; qq < 12; ++qq) {
        int o = tid + qq * 256;           // o = tag*1024 + i*32 + j
        int tg = o >> 10, ij = o & 1023;
        int i2 = ij >> 5, j = ij & 31;
        hw[o] = hist[(i2 << 8) | (tg << 6) | ((j + 3 * i2) & 31)];
    }
}

// ---- features + weighted offset average, one block per image ----
__global__ __launch_bounds__(256) void feature_out_kernel(
    const uint* __restrict__ wire, float* __restrict__ out) {
    const int b = blockIdx.x;
    __shared__ uint cnt[NUQ][1024];       // 24 KB
    __shared__ float fred[NUQ][4];
    const int tid = threadIdx.x, wid = tid >> 6, lane = tid & 63;

    for (int u = wid; u < NUQ; u += 4) {
        const int tg = (u < 3) ? u : u - 3;
        const int sh = (u < 3) ? 0 : 16;
        const uint* p = wire + (size_t)b * (8 * 3072) + tg * 1024;
        for (int ij = lane; ij < 1024; ij += 64) {
            uint acc = 0;
            #pragma unroll
            for (int st = 0; st < 8; ++st)
                acc += (p[(size_t)st * 3072 + ij] >> sh) & 0xFFFFu;
            cnt[u][ij] = acc;
        }
    }
    __syncthreads();

    for (int u = wid; u < NUQ; u += 4) {
        const float inv_total = 1.0f / (2.0f * NPAIRS[u]);
        float c_sum = 0, h_sum = 0, e_sum = 0, m1 = 0, m2 = 0, m12 = 0;
        for (int k = lane; k < 1024; k += 64) {
            int i = k >> 5, j = k & 31;
            float sym = (float)(cnt[u][k] + cnt[u][(j << 5) | i]);
            float P = sym * inv_total;
            float d = (float)(i - j);
            float d2 = d * d;
            float fi = (float)i, fj = (float)j;
            c_sum += P * d2;
            h_sum += P / (1.0f + d2);
            e_sum += P * P;
            m1 += P * fi; m2 += P * fi * fi; m12 += P * fi * fj;
        }
        #pragma unroll
        for (int sft = 32; sft > 0; sft >>= 1) {
            c_sum += __shfl_down(c_sum, sft);
            h_sum += __shfl_down(h_sum, sft);
            e_sum += __shfl_down(e_sum, sft);
            m1 += __shfl_down(m1, sft);
            m2 += __shfl_down(m2, sft);
            m12 += __shfl_down(m12, sft);
        }
        if (lane == 0) {
            float mu = m1, var = m2 - mu * mu, cov = m12 - mu * mu;
            float corr = (var > 1e-15f) ? cov / var : 1.0f;  // std_i*std_j = var
            fred[u][0] = c_sum; fred[u][1] = h_sum;
            fred[u][2] = sqrtf(e_sum); fred[u][3] = corr;
        }
    }
    __syncthreads();
    if (tid < 4) {
        float acc = 0.f;
        #pragma unroll
        for (int u = 0; u < NUQ; ++u) acc += UOFF_W[u] * fred[u][tid];
        out[tid * NIMG + b] = acc * 0.125f;
    }
}

extern "C" void kernel_launch(void* const* d_in, const int* in_sizes, int n_in,
                              void* d_out, int out_size, void* d_ws, size_t ws_size,
                              hipStream_t stream) {
    const float* images = (const float*)d_in[0];
    float* out = (float*)d_out;
    uint* wire = (uint*)d_ws;             // 512 blocks x 3072 u32 = 6.3 MB

    glcm_fused<<<NIMG * 8, 256, 0, stream>>>(images, wire);
    feature_out_kernel<<<NIMG, 256, 0, stream>>>(wire, out);
}

// Round 11
// 70.779 us; speedup vs baseline: 1.1509x; 1.0461x over previous
//
#include <hip/hip_runtime.h>

typedef unsigned int uint;

#define HW (512 * 512)
#define NIMG 64
#define NUQ 6
#define RSTRIDE 528               // ring row: 512 px + 16 sentinel bytes
#define RINGB 32768               // ring base (16 rows x 528 = 8448 B)
#define SMEMB (32768 + 16 * RSTRIDE)   // 41216

// 8 reference offsets -> 6 unique, weighted; (1,-1) stored as (-1,1)
// (transpose-equivalent under final P+P^T symmetrization).
// tag0: u0 (0,1) lo, u3 (-1,1) hi | tag1: u1 (1,1) lo, u4 (0,2) hi
// tag2: u2 (1,0) lo, u5 (2,0) hi
__device__ __constant__ float UOFF_W[NUQ] = {1.f, 2.f, 1.f, 2.f, 1.f, 1.f};
__device__ __constant__ float NPAIRS[NUQ] = {
    512.f * 511.f, 511.f * 511.f, 511.f * 512.f,
    511.f * 511.f, 512.f * 510.f, 510.f * 512.f};

__device__ __forceinline__ uint q1f(float a, float b, float c) {
    float t = fmaf(a + b + c, 5.1666665f, 15.5f);   // ((a+b+c)/3+1)*0.5*31
    t = fminf(fmaxf(t, 0.0f), 31.0f);
    return (uint)t;                                  // trunc = astype(int32)
}

// ---- fused: R4 skeleton (reg staging, hist c-2, 1 barrier/chunk) ----
__global__ __launch_bounds__(256) void glcm_fused(
    const float* __restrict__ in, uint* __restrict__ wire) {
    __shared__ __align__(16) unsigned char smem[SMEMB];
    const int tid = threadIdx.x;
    const int b = blockIdx.x >> 3;
    const int sp = blockIdx.x & 7;
    const int rs = sp * 64;               // 64 anchor rows per block
    const float* ib = in + (size_t)b * (3 * HW);
    const int lrow = tid >> 6;            // row within 4-row chunk
    const int lcol = (tid & 63) << 3;     // 8 px per thread

    {   // zero 32 KB hist (junk half included)
        uint4 z = make_uint4(0, 0, 0, 0);
        #pragma unroll
        for (int q = 0; q < 8; ++q)
            *(uint4*)(smem + tid * 16 + q * 4096) = z;
    }
    __syncthreads();

    float4 A0, B0, A1, B1, A2, B2;

    // issue 6 float4 loads for chunk c (rows rs-2+4c .. +3); use deferred
    auto issueL = [&](int c) {
        int R = rs - 2 + 4 * c + lrow;
        int Rc = min(max(R, 0), 511);     // clamped rows loaded, never written
        const float* p = ib + ((size_t)Rc << 9) + lcol;
        A0 = *(const float4*)(p);
        B0 = *(const float4*)(p + 4);
        A1 = *(const float4*)(p + HW);
        B1 = *(const float4*)(p + HW + 4);
        A2 = *(const float4*)(p + 2 * HW);
        B2 = *(const float4*)(p + 2 * HW + 4);
    };

    // quantize chunk c into ring (bytes pre-shifted <<2) + sentinel pads
    auto quantW = [&](int c) {
        int R = rs - 2 + 4 * c + lrow;
        if (R >= 0 && R <= 511) {
            uint q0 = (q1f(A0.x, A1.x, A2.x) << 2)
                    | (q1f(A0.y, A1.y, A2.y) << 10)
                    | (q1f(A0.z, A1.z, A2.z) << 18)
                    | (q1f(A0.w, A1.w, A2.w) << 26);
            uint q1_ = (q1f(B0.x, B1.x, B2.x) << 2)
                     | (q1f(B0.y, B1.y, B2.y) << 10)
                     | (q1f(B0.z, B1.z, B2.z) << 18)
                     | (q1f(B0.w, B1.w, B2.w) << 26);
            unsigned char* rw = smem + RINGB + ((R - rs + 2) & 15) * RSTRIDE;
            *(uint2*)(rw + lcol) = make_uint2(q0, q1_);
            if ((tid & 63) == 63)         // sentinel cols 512..527
                *(uint4*)(rw + 512) = make_uint4(0x80808080u, 0x80808080u,
                                                 0x80808080u, 0x80808080u);
        }
    };

    // histogram chunk h: anchors rs+4h .. +3; 2 rounds x (2 rows x 128 dwords)
    auto histC = [&](int h) {
        #pragma unroll
        for (int rr = 0; rr < 2; ++rr) {
            const int R = rs + 4 * h + 2 * rr + (tid >> 7);   // wave-uniform
            const int v = R - rs + 2;
            const int dq = tid & 127;
            const unsigned char* ring = smem + RINGB;
            const uint* rowL   = (const uint*)(ring + ((v)     & 15) * RSTRIDE);
            const uint* rowLm  = (const uint*)(ring + ((v - 1) & 15) * RSTRIDE);
            const uint* rowLp  = (const uint*)(ring + ((v + 1) & 15) * RSTRIDE);
            const uint* rowLpp = (const uint*)(ring + ((v + 2) & 15) * RSTRIDE);
            uint A  = rowL[dq],  A1 = rowL[dq + 1];   // dq=127 -> [128] = pad
            uint Bm = rowLp[dq], B1 = rowLp[dq + 1];
            uint Cm = rowLm[dq], C1 = rowLm[dq + 1];
            uint D  = rowLpp[dq];

            // stored j-field = (j + 3i) & 31 (bank mix, bijective per i);
            // perm {i<<2, j'<<2|sent} -> addr = i<<10 | sent<<7 | j'<<2;
            // sentinel bit7 -> junk half of the 256B (i,tag) block.
            auto pp4 = [&](uint IW, uint JW, int tagoff, uint inc) {
                uint jm = (JW >> 2) & 0x1F1F1F1Fu;
                uint im = (IW >> 2) & 0x1F1F1F1Fu;
                uint s  = (jm + im + (im << 1)) & 0x1F1F1F1Fu;  // j+3i, no carry
                uint J2 = (s << 2) | (JW & 0x80808080u);
                uint a0 = __builtin_amdgcn_perm(IW, J2, 0x0C0C0400u);
                uint a1 = __builtin_amdgcn_perm(IW, J2, 0x0C0C0501u);
                uint a2 = __builtin_amdgcn_perm(IW, J2, 0x0C0C0602u);
                uint a3 = __builtin_amdgcn_perm(IW, J2, 0x0C0C0703u);
                atomicAdd((uint*)(smem + tagoff + a0), inc);
                atomicAdd((uint*)(smem + tagoff + a1), inc);
                atomicAdd((uint*)(smem + tagoff + a2), inc);
                atomicAdd((uint*)(smem + tagoff + a3), inc);
            };
            pp4(A, __builtin_amdgcn_alignbyte(A1, A, 1), 0, 1u);             // u0 (0,1)
            if (R < 511) {
                pp4(A, __builtin_amdgcn_alignbyte(B1, Bm, 1), 256, 1u);      // u1 (1,1)
                pp4(A, Bm, 512, 1u);                                         // u2 (1,0)
            }
            if (R >= 1)
                pp4(A, __builtin_amdgcn_alignbyte(C1, Cm, 1), 0, 65536u);    // u3 (-1,1)
            pp4(A, __builtin_amdgcn_alignbyte(A1, A, 2), 256, 65536u);       // u4 (0,2)
            if (R < 510) pp4(A, D, 512, 65536u);                             // u5 (2,0)
        }
    };

    // chunks c=0..16 load rows rs-2 .. rs+65; hist h=0..15 covers anchors
    for (int c = 0; c <= 17; ++c) {
        if (c <= 16) issueL(c);           // loads issue; vmcnt waited in quantW
        if (c >= 2) histC(c - 2);         // DS+VALU work hides load latency
        if (c <= 16) quantW(c);
        __syncthreads();
    }

    // flush valid bins -> 3072-dword wire, un-mixing the stored j-field
    uint* hw = wire + (size_t)blockIdx.x * 3072;
    const uint* hist = (const uint*)smem;
    #pragma unroll
    for (int qq = 0; qq < 12; ++qq) {
        int o = tid + qq * 256;           // o = tag*1024 + i*32 + j
        int tg = o >> 10, ij = o & 1023;
        int i2 = ij >> 5, j = ij & 31;
        hw[o] = hist[(i2 << 8) | (tg << 6) | ((j + 3 * i2) & 31)];
    }
}

// ---- features + weighted offset average, one block per image ----
__global__ __launch_bounds__(256) void feature_out_kernel(
    const uint* __restrict__ wire, float* __restrict__ out) {
    const int b = blockIdx.x;
    __shared__ uint cnt[NUQ][1024];       // 24 KB
    __shared__ float fred[NUQ][4];
    const int tid = threadIdx.x, wid = tid >> 6, lane = tid & 63;

    for (int u = wid; u < NUQ; u += 4) {
        const int tg = (u < 3) ? u : u - 3;
        const int sh = (u < 3) ? 0 : 16;
        const uint* p = wire + (size_t)b * (8 * 3072) + tg * 1024;
        for (int ij = lane; ij < 1024; ij += 64) {
            uint acc = 0;
            #pragma unroll
            for (int st = 0; st < 8; ++st)
                acc += (p[(size_t)st * 3072 + ij] >> sh) & 0xFFFFu;
            cnt[u][ij] = acc;
        }
    }
    __syncthreads();

    for (int u = wid; u < NUQ; u += 4) {
        const float inv_total = 1.0f / (2.0f * NPAIRS[u]);
        float c_sum = 0, h_sum = 0, e_sum = 0, m1 = 0, m2 = 0, m12 = 0;
        for (int k = lane; k < 1024; k += 64) {
            int i = k >> 5, j = k & 31;
            float sym = (float)(cnt[u][k] + cnt[u][(j << 5) | i]);
            float P = sym * inv_total;
            float d = (float)(i - j);
            float d2 = d * d;
            float fi = (float)i, fj = (float)j;
            c_sum += P * d2;
            h_sum += P / (1.0f + d2);
            e_sum += P * P;
            m1 += P * fi; m2 += P * fi * fi; m12 += P * fi * fj;
        }
        #pragma unroll
        for (int sft = 32; sft > 0; sft >>= 1) {
            c_sum += __shfl_down(c_sum, sft);
            h_sum += __shfl_down(h_sum, sft);
            e_sum += __shfl_down(e_sum, sft);
            m1 += __shfl_down(m1, sft);
            m2 += __shfl_down(m2, sft);
            m12 += __shfl_down(m12, sft);
        }
        if (lane == 0) {
            float mu = m1, var = m2 - mu * mu, cov = m12 - mu * mu;
            float corr = (var > 1e-15f) ? cov / var : 1.0f;  // std_i*std_j = var
            fred[u][0] = c_sum; fred[u][1] = h_sum;
            fred[u][2] = sqrtf(e_sum); fred[u][3] = corr;
        }
    }
    __syncthreads();
    if (tid < 4) {
        float acc = 0.f;
        #pragma unroll
        for (int u = 0; u < NUQ; ++u) acc += UOFF_W[u] * fred[u][tid];
        out[tid * NIMG + b] = acc * 0.125f;
    }
}

extern "C" void kernel_launch(void* const* d_in, const int* in_sizes, int n_in,
                              void* d_out, int out_size, void* d_ws, size_t ws_size,
                              hipStream_t stream) {
    const float* images = (const float*)d_in[0];
    float* out = (float*)d_out;
    uint* wire = (uint*)d_ws;             // 512 blocks x 3072 u32 = 6.3 MB

    glcm_fused<<<NIMG * 8, 256, 0, stream>>>(images, wire);
    feature_out_kernel<<<NIMG, 256, 0, stream>>>(wire, out);
}